// Round 6
// baseline (364.910 us; speedup 1.0000x reference)
//
#include <hip/hip_runtime.h>
#include <hip/hip_cooperative_groups.h>
#include <cstdint>
#include <cstddef>

namespace cg = cooperative_groups;

#define BPTS    131072
#define D_DIM   128
#define G_GR    128
#define NL      8
#define GD      (G_GR * D_DIM)       // 16384 floats = 64 KiB
#define NBLK    256                  // 1 block per CU (cooperative co-residency)
#define TPB     1024                 // 16 waves
#define PPB     (BPTS / NBLK)        // 512 contiguous points per block
#define GPW     (G_GR / (TPB / 64))  // 8 groups per wave

// d += dpp_shifted(d); pure VALU, no DS pipe.
__device__ __forceinline__ float dpp_add(float d, const int ctrl) {
    int s;
    switch (ctrl) {   // ctrl must be an ICE for the builtin
    case 0x111: s = __builtin_amdgcn_update_dpp(0, __float_as_int(d), 0x111, 0xf, 0xf, true); break;
    case 0x112: s = __builtin_amdgcn_update_dpp(0, __float_as_int(d), 0x112, 0xf, 0xf, true); break;
    case 0x114: s = __builtin_amdgcn_update_dpp(0, __float_as_int(d), 0x114, 0xf, 0xf, true); break;
    case 0x118: s = __builtin_amdgcn_update_dpp(0, __float_as_int(d), 0x118, 0xf, 0xf, true); break;
    case 0x142: s = __builtin_amdgcn_update_dpp(0, __float_as_int(d), 0x142, 0xf, 0xf, true); break;
    default:    s = __builtin_amdgcn_update_dpp(0, __float_as_int(d), 0x143, 0xf, 0xf, true); break;
    }
    return d + __int_as_float(s);
}

// full 64-lane sum -> result valid in lane 63
__device__ __forceinline__ float sum64(float d) {
    d = dpp_add(d, 0x111);
    d = dpp_add(d, 0x112);
    d = dpp_add(d, 0x114);
    d = dpp_add(d, 0x118);   // lane 15/31/47/63 hold 16-lane sums
    d = dpp_add(d, 0x142);   // lane 31/63 hold 32-lane sums
    d = dpp_add(d, 0x143);   // lane 63 holds 64-lane sum
    return d;
}

// ---------------------------------------------------------------------------
// Single cooperative kernel. LDS bucket lists persist across ALL phases.
// P1 partial centroids -> P2 centroid reduce -> P3 distances (+coc) ->
// P4 per-group folds -> P5 scalar tail. 4 grid syncs, 1 dispatch.
// ---------------------------------------------------------------------------
__global__ __launch_bounds__(TPB) void k_all(const float* __restrict__ Xf,
                                             const int* __restrict__ sub,
                                             const int* __restrict__ lab,
                                             float* __restrict__ cpart,
                                             int* __restrict__ hpart,
                                             float* __restrict__ centroid,
                                             float* __restrict__ countsf,
                                             float* __restrict__ cocG,
                                             float* __restrict__ dpart,
                                             float* __restrict__ densp,
                                             float* __restrict__ dotv,
                                             float* __restrict__ out) {
    cg::grid_group grid = cg::this_grid();
    __shared__ int   glist[PPB];      // persists P1 -> P3
    __shared__ int   goff[G_GR];
    __shared__ int   hist[G_GR];
    __shared__ int   cursor[G_GR];
    __shared__ int   scan[G_GR];
    __shared__ float fred[TPB];       // generic float scratch
    __shared__ float cf2s;

    int t = threadIdx.x, blk = blockIdx.x;
    int lane = t & 63, w = t >> 6;
    int pbase = blk * PPB;

    // ======================= P1: lists + partial sums =======================
    if (t < G_GR) hist[t] = 0;
    __syncthreads();
    int myg = -1;
    if (t < PPB) {
        myg = sub[pbase + t] * NL + lab[pbase + t];
        atomicAdd(&hist[myg], 1);
    }
    __syncthreads();
    if (t < G_GR) scan[t] = hist[t];
    __syncthreads();
    for (int s = 1; s < G_GR; s <<= 1) {
        int v = 0;
        if (t < G_GR) { v = scan[t]; if (t >= s) v += scan[t - s]; }
        __syncthreads();
        if (t < G_GR) scan[t] = v;
        __syncthreads();
    }
    if (t < G_GR) { goff[t] = scan[t] - hist[t]; cursor[t] = scan[t] - hist[t]; }
    __syncthreads();
    if (t < PPB) {
        int pos = atomicAdd(&cursor[myg], 1);
        glist[pos] = t;
    }
    __syncthreads();
    if (t < G_GR) hpart[blk * G_GR + t] = hist[t];

    for (int gi = 0; gi < GPW; ++gi) {
        int g = w * GPW + gi;
        int s = goff[g], n = hist[g];
        float ax = 0.f, ay = 0.f;
        int k = 0;
        for (; k + 4 <= n; k += 4) {                 // 8 loads in flight
            int p0 = pbase + glist[s + k + 0];
            int p1 = pbase + glist[s + k + 1];
            int p2 = pbase + glist[s + k + 2];
            int p3 = pbase + glist[s + k + 3];
            const float* r0 = Xf + (size_t)p0 * 256;
            const float* r1 = Xf + (size_t)p1 * 256;
            const float* r2 = Xf + (size_t)p2 * 256;
            const float* r3 = Xf + (size_t)p3 * 256;
            float2 a0 = *(const float2*)(r0 + 2 * lane);
            float2 b0 = *(const float2*)(r0 + 128 + 2 * lane);
            float2 a1 = *(const float2*)(r1 + 2 * lane);
            float2 b1 = *(const float2*)(r1 + 128 + 2 * lane);
            float2 a2 = *(const float2*)(r2 + 2 * lane);
            float2 b2 = *(const float2*)(r2 + 128 + 2 * lane);
            float2 a3 = *(const float2*)(r3 + 2 * lane);
            float2 b3 = *(const float2*)(r3 + 128 + 2 * lane);
            ax += (a0.x + b0.x) + (a1.x + b1.x) + (a2.x + b2.x) + (a3.x + b3.x);
            ay += (a0.y + b0.y) + (a1.y + b1.y) + (a2.y + b2.y) + (a3.y + b3.y);
        }
        for (; k < n; ++k) {
            int p = pbase + glist[s + k];
            const float* r = Xf + (size_t)p * 256;
            float2 a = *(const float2*)(r + 2 * lane);
            float2 b = *(const float2*)(r + 128 + 2 * lane);
            ax += a.x + b.x;
            ay += a.y + b.y;
        }
        float2 o; o.x = ax; o.y = ay;
        *(float2*)(cpart + (size_t)blk * GD + (size_t)g * D_DIM + 2 * lane) = o;
    }
    grid.sync();

    // ======================= P2: centroid reduce ===========================
    {   // block = (g, half-of-D)
        int g = blk >> 1, h = blk & 1;
        int dl = t & 63, bs = t >> 6;             // 16 slices x 64 lanes
        int d = h * 64 + dl;
        float a0 = 0.f, a1 = 0.f, a2 = 0.f, a3 = 0.f;
        for (int b = bs; b < NBLK; b += 64) {     // 4 loads in flight
            a0 += cpart[(size_t)(b)      * GD + g * D_DIM + d];
            a1 += cpart[(size_t)(b + 16) * GD + g * D_DIM + d];
            a2 += cpart[(size_t)(b + 32) * GD + g * D_DIM + d];
            a3 += cpart[(size_t)(b + 48) * GD + g * D_DIM + d];
        }
        fred[t] = (a0 + a1) + (a2 + a3);
        if (t < G_GR) {                            // counts (2 strided loads)
            int hacc = hpart[t * G_GR + g] + hpart[(t + 128) * G_GR + g];
            scan[t] = hacc;
        }
        __syncthreads();
        if (t == 0) {
            int n = 0;
            for (int i = 0; i < G_GR; ++i) n += scan[i];
            cf2s = 2.f * (float)n;
            if (h == 0) countsf[g] = cf2s;
        }
        __syncthreads();
        if (t < 64) {
            float v = 0.f;
#pragma unroll
            for (int r = 0; r < 16; ++r) v += fred[r * 64 + t];
            float cf2 = cf2s;
            centroid[g * D_DIM + h * 64 + t] = (cf2 > 0.f) ? v / cf2 : 0.f;
        }
    }
    grid.sync();

    // ======================= P3: distances (+coc by block 0) ===============
    for (int gi = 0; gi < GPW; ++gi) {
        int g = w * GPW + gi;
        int s = goff[g], n = hist[g];              // LDS lists still live
        float2 c = *(const float2*)(centroid + (size_t)g * D_DIM + 2 * lane);
        float sacc = 0.f;
        int k = 0;
        for (; k + 2 <= n; k += 2) {
            int p0 = pbase + glist[s + k];
            int p1 = pbase + glist[s + k + 1];
            const float* r0 = Xf + (size_t)p0 * 256;
            const float* r1 = Xf + (size_t)p1 * 256;
            float2 a0 = *(const float2*)(r0 + 2 * lane);
            float2 b0 = *(const float2*)(r0 + 128 + 2 * lane);
            float2 a1 = *(const float2*)(r1 + 2 * lane);
            float2 b1 = *(const float2*)(r1 + 128 + 2 * lane);
            float e0 = a0.x - c.x, e1 = a0.y - c.y;
            float f0 = b0.x - c.x, f1 = b0.y - c.y;
            float g0 = a1.x - c.x, g1 = a1.y - c.y;
            float h0 = b1.x - c.x, h1 = b1.y - c.y;
            float d0 = sum64(e0 * e0 + e1 * e1);
            float d1 = sum64(f0 * f0 + f1 * f1);
            float d2 = sum64(g0 * g0 + g1 * g1);
            float d3 = sum64(h0 * h0 + h1 * h1);
            sacc += (sqrtf(sqrtf(d0)) + sqrtf(sqrtf(d1)))
                  + (sqrtf(sqrtf(d2)) + sqrtf(sqrtf(d3)));
        }
        if (k < n) {
            int p = pbase + glist[s + k];
            const float* r = Xf + (size_t)p * 256;
            float2 a = *(const float2*)(r + 2 * lane);
            float2 b = *(const float2*)(r + 128 + 2 * lane);
            float e0 = a.x - c.x, e1 = a.y - c.y;
            float f0 = b.x - c.x, f1 = b.y - c.y;
            float d0 = sum64(e0 * e0 + e1 * e1);
            float d1 = sum64(f0 * f0 + f1 * f1);
            sacc += sqrtf(sqrtf(d0)) + sqrtf(sqrtf(d1));
        }
        if (lane == 63) dpart[(size_t)g * NBLK + blk] = sacc;  // [g][blk]
    }
    if (blk == 0) {                                // coc (needs only centroid)
        int col = t & 127, q = t >> 7;             // 8 slices
        float cs = 0.f;
        for (int g = q; g < G_GR; g += 8) cs += centroid[g * D_DIM + col];
        __syncthreads();
        fred[q * 128 + col] = cs;
        __syncthreads();
        if (t < D_DIM) {
            float v = 0.f;
#pragma unroll
            for (int r = 0; r < 8; ++r) v += fred[r * 128 + t];
            cocG[t] = v / 128.f;
        }
    }
    grid.sync();

    // ======================= P4: per-group folds ===========================
    if (blk < G_GR) {
        int g = blk;
        fred[t] = (t < NBLK) ? dpart[(size_t)g * NBLK + t] : 0.f;
        __syncthreads();
        for (int s = 512; s > 0; s >>= 1) {
            if (t < s) fred[t] += fred[t + s];
            __syncthreads();
        }
        float dsum = fred[0];
        float cnt = countsf[g];
        if (t == 0)
            densp[g] = (cnt > 1.f) ? (dsum / cnt) / logf(cnt + 10.f) : 0.f;
        __syncthreads();
        fred[t] = (t < D_DIM) ? centroid[(size_t)g * D_DIM + t] * cocG[t] : 0.f;
        __syncthreads();
        for (int s = 512; s > 0; s >>= 1) {
            if (t < s) fred[t] += fred[t + s];
            __syncthreads();
        }
        if (t == 0) dotv[g] = fred[0];
    }
    grid.sync();

    // ======================= P5: scalar tail (block 0) =====================
    if (blk == 0) {
        float* srt = fred;          // [128]
        float* red = fred + 128;    // [128]
        float dens = 0.f, cnt = 0.f;
        if (t < G_GR) {
            cnt = countsf[t];
            dens = densp[t];
            red[t] = dens;
        }
        __syncthreads();
        for (int s = 64; s > 0; s >>= 1) {
            if (t < s) red[t] = fmaxf(red[t], red[t + s]);
            __syncthreads();
        }
        float dmax = red[0];
        __syncthreads();
        if (t < G_GR && !(cnt > 1.f)) dens = dmax;
        if (t < G_GR) srt[t] = dens;
        __syncthreads();
        for (int k = 2; k <= G_GR; k <<= 1) {
            for (int j = k >> 1; j > 0; j >>= 1) {
                int ixj = t ^ j;
                if (t < G_GR && ixj > t) {
                    float a = srt[t], b = srt[ixj];
                    bool up = ((t & k) == 0);
                    if ((a > b) == up) { srt[t] = b; srt[ixj] = a; }
                }
                __syncthreads();
            }
        }
        double p10 = 0.10 * 127.0, p90 = 0.90 * 127.0;
        int   i10 = (int)p10,           i90 = (int)p90;
        float f10 = (float)(p10 - i10), f90 = (float)(p90 - i90);
        float lo = srt[i10] + f10 * (srt[i10 + 1] - srt[i10]);
        float hi = srt[i90] + f90 * (srt[i90 + 1] - srt[i90]);
        if (t < G_GR) dens = fminf(fmaxf(dens, lo), hi);
        __syncthreads();
        if (t < G_GR) red[t] = dens;
        __syncthreads();
        for (int s = 64; s > 0; s >>= 1) {
            if (t < s) red[t] += red[t + s];
            __syncthreads();
        }
        float dmean = red[0] / 128.f;
        __syncthreads();
        float sim = 0.f;
        if (t < G_GR) {
            float dv = 0.1f * dens / dmean;
            sim = expf(dotv[t] / dv);
            red[t] = sim;
        }
        __syncthreads();
        for (int s = 64; s > 0; s >>= 1) {
            if (t < s) red[t] = fmaxf(red[t], red[t + s]);
            __syncthreads();
        }
        float smax = red[0];
        __syncthreads();
        if (t < G_GR) red[t] = sim - smax;
        __syncthreads();
        for (int s = 64; s > 0; s >>= 1) {
            if (t < s) red[t] += red[t + s];
            __syncthreads();
        }
        if (t == 0) out[0] = -(red[0] / 128.f);
    }
}

// ---------------------------------------------------------------------------
extern "C" void kernel_launch(void* const* d_in, const int* in_sizes, int n_in,
                              void* d_out, int out_size, void* d_ws, size_t ws_size,
                              hipStream_t stream) {
    const float*  Xf      = (const float*)d_in[0];
    const int*    subject = (const int*)d_in[1];
    const int*    labels  = (const int*)d_in[2];
    float*        out     = (float*)d_out;
    char*         ws      = (char*)d_ws;

    size_t o = 0;
    float* cpart    = (float*)(ws + o); o += (size_t)NBLK * GD * 4;     // 16 MiB
    int*   hpart    = (int*)(ws + o);   o += (size_t)NBLK * G_GR * 4;   // 128 KiB
    float* centroid = (float*)(ws + o); o += (size_t)GD * 4;            // 64 KiB
    float* countsf  = (float*)(ws + o); o += 512;
    float* cocG     = (float*)(ws + o); o += 512;
    float* dpart    = (float*)(ws + o); o += (size_t)G_GR * NBLK * 4;   // 128 KiB
    float* densp    = (float*)(ws + o); o += 512;
    float* dotv     = (float*)(ws + o); o += 512;

    void* args[] = {(void*)&Xf, (void*)&subject, (void*)&labels, (void*)&cpart,
                    (void*)&hpart, (void*)&centroid, (void*)&countsf, (void*)&cocG,
                    (void*)&dpart, (void*)&densp, (void*)&dotv, (void*)&out};
    hipLaunchCooperativeKernel((const void*)k_all, dim3(NBLK), dim3(TPB),
                               args, 0, stream);
}

// Round 7
// 248.156 us; speedup vs baseline: 1.4705x; 1.4705x over previous
//
#include <hip/hip_runtime.h>
#include <cstdint>
#include <cstddef>

#define BPTS    131072
#define D_DIM   128
#define G_GR    128
#define NL      8
#define NSLC    16                 // slices per group -> 2048 heavy blocks
#define PERMBUF 128                // max slice len ~72 (count ~1024±32, /16)
#define NBLK_S  64                 // sort blocks
#define PPB     (BPTS / NBLK_S)    // 2048 contiguous points per sort block

// d += dpp_shifted(d); pure VALU, no DS pipe.
// 0x111/0x112/0x114/0x118 = row_shr 1/2/4/8; 0x142 = row_bcast15.
__device__ __forceinline__ float dpp_add(float d, const int ctrl) {
    int s;
    switch (ctrl) {   // ctrl must be an ICE for the builtin
    case 0x111: s = __builtin_amdgcn_update_dpp(0, __float_as_int(d), 0x111, 0xf, 0xf, true); break;
    case 0x112: s = __builtin_amdgcn_update_dpp(0, __float_as_int(d), 0x112, 0xf, 0xf, true); break;
    case 0x114: s = __builtin_amdgcn_update_dpp(0, __float_as_int(d), 0x114, 0xf, 0xf, true); break;
    case 0x118: s = __builtin_amdgcn_update_dpp(0, __float_as_int(d), 0x118, 0xf, 0xf, true); break;
    case 0x142: s = __builtin_amdgcn_update_dpp(0, __float_as_int(d), 0x142, 0xf, 0xf, true); break;
    default:    s = __builtin_amdgcn_update_dpp(0, __float_as_int(d), 0x143, 0xf, 0xf, true); break;
    }
    return d + __int_as_float(s);
}

// 32-lane-half sums: after this, lane 31 = sum(lanes 0..31), lane 63 = sum(32..63)
__device__ __forceinline__ float sum32h(float d) {
    d = dpp_add(d, 0x111);
    d = dpp_add(d, 0x112);
    d = dpp_add(d, 0x114);
    d = dpp_add(d, 0x118);   // lane 15/31/47/63 hold 16-lane sums
    d = dpp_add(d, 0x142);   // lane 31/63 hold 32-lane sums
    return d;
}

// full 64-lane sum -> result valid in lane 63
__device__ __forceinline__ float sum64(float d) {
    d = sum32h(d);
    d = dpp_add(d, 0x143);
    return d;
}

// ---------------------------------------------------------------------------
// k_hist: per-block histogram of group ids -> hblk[blk][128]
// ---------------------------------------------------------------------------
__global__ __launch_bounds__(256) void k_hist(const int* __restrict__ sub,
                                              const int* __restrict__ lab,
                                              int* __restrict__ hblk) {
    __shared__ int h[G_GR];
    int t = threadIdx.x, blk = blockIdx.x;
    if (t < G_GR) h[t] = 0;
    __syncthreads();
    int b0 = blk * PPB;
    for (int i = t; i < PPB; i += 256)
        atomicAdd(&h[sub[b0 + i] * NL + lab[b0 + i]], 1);
    __syncthreads();
    if (t < G_GR) hblk[blk * G_GR + t] = h[t];
}

// ---------------------------------------------------------------------------
// k_scatter: fused prefix (recomputed per block from hblk, deterministic) +
// scatter via per-block LDS cursor. Block 0 publishes counts/offsets/countsf.
// ---------------------------------------------------------------------------
__global__ __launch_bounds__(256) void k_scatter(const int* __restrict__ sub,
                                                 const int* __restrict__ lab,
                                                 const int* __restrict__ hblk,
                                                 int* __restrict__ counts,
                                                 int* __restrict__ offsets,
                                                 float* __restrict__ countsf,
                                                 int* __restrict__ perm) {
    __shared__ int tot[G_GR];
    __shared__ int cur[G_GR];
    int t = threadIdx.x, blk = blockIdx.x;
    if (t < G_GR) {
        int tt = 0, mine = 0;
        for (int b = 0; b < NBLK_S; ++b) {
            int v = hblk[b * G_GR + t];
            tt += v;
            if (b < blk) mine += v;
        }
        tot[t] = tt;
        cur[t] = mine;
    }
    __syncthreads();
    if (t < G_GR) {
        int off = 0;
        for (int j = 0; j < t; ++j) off += tot[j];
        cur[t] += off;
        if (blk == 0) {
            counts[t]  = tot[t];
            offsets[t] = off;
            countsf[t] = 2.0f * (float)tot[t];
        }
    }
    __syncthreads();
    int b0 = blk * PPB;
    for (int i = t; i < PPB; i += 256) {
        int p = b0 + i;
        int g = sub[p] * NL + lab[p];
        int s = atomicAdd(&cur[g], 1);   // LDS-only cursor
        perm[s] = p;
    }
}

// ---------------------------------------------------------------------------
// k_psum: block (g,s) sums its slice of group g. Wave-per-point, batched
// unroll-8 float4 loads, register accumulate, zero atomics.
// ---------------------------------------------------------------------------
__global__ __launch_bounds__(256) void k_psum(const float4* __restrict__ X4,
                                              const int* __restrict__ perm,
                                              const int* __restrict__ offsets,
                                              const int* __restrict__ counts,
                                              float* __restrict__ part) {
    __shared__ int   pbuf[PERMBUF];
    __shared__ float red[4 * 256];
    int g = blockIdx.x >> 4, s = blockIdx.x & 15;
    int off = offsets[g], len = counts[g];
    int lo = off + (len * s) / NSLC;
    int hi = off + (len * (s + 1)) / NSLC;
    int slen = hi - lo;
    int t = threadIdx.x, lane = t & 63, w = t >> 6;

    for (int j = t; j < slen; j += 256) pbuf[j] = perm[lo + j];
    __syncthreads();

    float4 acc = make_float4(0.f, 0.f, 0.f, 0.f);
    for (int i = w * 8; i < slen; i += 32) {
        int idx[8];
#pragma unroll
        for (int u = 0; u < 8; ++u) {
            int j = i + u;
            idx[u] = pbuf[(j < slen) ? j : (slen - 1)];
        }
        float4 x[8];
#pragma unroll
        for (int u = 0; u < 8; ++u) x[u] = X4[(size_t)idx[u] * 64 + lane];
#pragma unroll
        for (int u = 0; u < 8; ++u) {
            if (i + u < slen) {
                acc.x += x[u].x; acc.y += x[u].y;
                acc.z += x[u].z; acc.w += x[u].w;
            }
        }
    }
    red[w * 256 + lane * 4 + 0] = acc.x;
    red[w * 256 + lane * 4 + 1] = acc.y;
    red[w * 256 + lane * 4 + 2] = acc.z;
    red[w * 256 + lane * 4 + 3] = acc.w;
    __syncthreads();
    if (t < 128) {                        // fold 4 wave copies + the two views
        float v = 0.f;
        for (int r = 0; r < 4; ++r)
            v += red[r * 256 + t] + red[r * 256 + t + 128];
        part[(size_t)blockIdx.x * 128 + t] = v;
    }
}

// ---------------------------------------------------------------------------
// k_dist: fused centroid reduce (deterministic, redundant per slice; slice 0
// publishes centroid for k_final) + per-point ||x-c|| via DPP 32-lane sums
// (VALU pipe, no DS butterfly); accumulate sqrt(||x-c||) per block.
// ---------------------------------------------------------------------------
__global__ __launch_bounds__(256) void k_dist(const float4* __restrict__ X4,
                                              const int* __restrict__ perm,
                                              const int* __restrict__ offsets,
                                              const int* __restrict__ counts,
                                              const float* __restrict__ part,
                                              float* __restrict__ centroid,
                                              float* __restrict__ dpart) {
    __shared__ int   pbuf[PERMBUF];
    __shared__ float cen[D_DIM];
    __shared__ float wsum[4];
    int g = blockIdx.x >> 4, s = blockIdx.x & 15;
    int off = offsets[g], len = counts[g];
    int lo = off + (len * s) / NSLC;
    int hi = off + (len * (s + 1)) / NSLC;
    int slen = hi - lo;
    int t = threadIdx.x, lane = t & 63, w = t >> 6;

    if (t < D_DIM) {                      // fused centroid reduce
        float v = 0.f;
        for (int s2 = 0; s2 < NSLC; ++s2)
            v += part[(size_t)(g * NSLC + s2) * 128 + t];
        float c = (len > 0) ? v / (2.0f * (float)len) : 0.f;
        cen[t] = c;
        if (s == 0) centroid[g * D_DIM + t] = c;
    }
    for (int j = t; j < slen; j += 256) pbuf[j] = perm[lo + j];
    __syncthreads();

    int cd = (lane & 31) * 4;
    float4 c = make_float4(cen[cd], cen[cd + 1], cen[cd + 2], cen[cd + 3]);

    float sacc = 0.f;                     // live only at lanes 31 / 63
    for (int i = w * 8; i < slen; i += 32) {
        int idx[8];
#pragma unroll
        for (int u = 0; u < 8; ++u) {
            int j = i + u;
            idx[u] = pbuf[(j < slen) ? j : (slen - 1)];
        }
        float4 x[8];
#pragma unroll
        for (int u = 0; u < 8; ++u) x[u] = X4[(size_t)idx[u] * 64 + lane];
#pragma unroll
        for (int u = 0; u < 8; ++u) {
            float dx = x[u].x - c.x, dy = x[u].y - c.y;
            float dz = x[u].z - c.z, dw = x[u].w - c.w;
            float d = dx * dx + dy * dy + dz * dz + dw * dw;
            d = sum32h(d);                // VALU DPP: lane31=view0, lane63=view1
            if (i + u < slen && (lane & 31) == 31)
                sacc += sqrtf(sqrtf(d));  // sqrt(||x-c||) per view
        }
    }
    float v0 = __int_as_float(__builtin_amdgcn_readlane(__float_as_int(sacc), 31));
    float v1 = __int_as_float(__builtin_amdgcn_readlane(__float_as_int(sacc), 63));
    if (lane == 0) wsum[w] = v0 + v1;     // fold the two views
    __syncthreads();
    if (t == 0) dpart[blockIdx.x] = wsum[0] + wsum[1] + wsum[2] + wsum[3];
}

// ---------------------------------------------------------------------------
// k_final: single block, 512 threads. dpart fold on t<128, percentile/clip,
// coc via 4-slice coalesced reduce, dot via 8 waves x DPP sum64 (no
// uncoalesced per-thread row walk).
// ---------------------------------------------------------------------------
__global__ __launch_bounds__(512) void k_final(const float* __restrict__ dpart,
                                               const float* __restrict__ countsf,
                                               const float* __restrict__ centroid,
                                               float* __restrict__ out) {
    __shared__ float sl4[4][G_GR];
    __shared__ float srt[G_GR];
    __shared__ float red[G_GR];
    __shared__ float cocs[D_DIM];
    __shared__ float dotv[G_GR];
    int t = threadIdx.x;
    int col = t & 127, q = t >> 7;            // 4 slices
    int lane = t & 63, w8 = t >> 6;           // 8 waves

    float dens = 0.f, cnt = 0.f;
    if (t < G_GR) {
        float ds = 0.f;
        for (int s = 0; s < NSLC; ++s) ds += dpart[t * NSLC + s];
        cnt = countsf[t];
        dens = (cnt > 1.f) ? (ds / cnt) / logf(cnt + 10.f) : 0.f;
        red[t] = dens;
    }
    __syncthreads();
    for (int s = 64; s > 0; s >>= 1) {
        if (t < s) red[t] = fmaxf(red[t], red[t + s]);
        __syncthreads();
    }
    float dmax = red[0];
    __syncthreads();
    if (t < G_GR && !(cnt > 1.f)) dens = dmax;

    // bitonic sort ascending over 128 entries
    if (t < G_GR) srt[t] = dens;
    __syncthreads();
    for (int k = 2; k <= G_GR; k <<= 1) {
        for (int j = k >> 1; j > 0; j >>= 1) {
            int ixj = t ^ j;
            if (t < G_GR && ixj > t) {
                float a = srt[t], b = srt[ixj];
                bool up = ((t & k) == 0);
                if ((a > b) == up) { srt[t] = b; srt[ixj] = a; }
            }
            __syncthreads();
        }
    }
    double p10 = 0.10 * 127.0, p90 = 0.90 * 127.0;
    int   i10 = (int)p10,           i90 = (int)p90;
    float f10 = (float)(p10 - i10), f90 = (float)(p90 - i90);
    float lo = srt[i10] + f10 * (srt[i10 + 1] - srt[i10]);
    float hi = srt[i90] + f90 * (srt[i90 + 1] - srt[i90]);
    if (t < G_GR) dens = fminf(fmaxf(dens, lo), hi);

    if (t < G_GR) red[t] = dens;
    __syncthreads();
    for (int s = 64; s > 0; s >>= 1) {
        if (t < s) red[t] += red[t + s];
        __syncthreads();
    }
    float dmean = red[0] / 128.f;
    __syncthreads();

    // coc: 4-slice coalesced column sum
    float cs = 0.f;
    for (int g = q; g < G_GR; g += 4) cs += centroid[g * D_DIM + col];
    sl4[q][col] = cs;
    __syncthreads();
    if (t < D_DIM)
        cocs[t] = (sl4[0][t] + sl4[1][t] + sl4[2][t] + sl4[3][t]) / 128.f;
    __syncthreads();

    // dot: 8 waves x 16 groups, DPP sum64 per group (coalesced loads)
    {
        float2 co = *(const float2*)&cocs[2 * lane];
        for (int i = 0; i < 16; ++i) {
            int g = w8 * 16 + i;
            float2 c = *(const float2*)(centroid + (size_t)g * D_DIM + 2 * lane);
            float p = c.x * co.x + c.y * co.y;
            float sm = sum64(p);
            if (lane == 63) dotv[g] = sm;
        }
    }
    __syncthreads();

    float sim = 0.f;
    if (t < G_GR) {
        float dv = 0.1f * dens / dmean;
        sim = expf(dotv[t] / dv);
        red[t] = sim;
    }
    __syncthreads();
    for (int s = 64; s > 0; s >>= 1) {
        if (t < s) red[t] = fmaxf(red[t], red[t + s]);
        __syncthreads();
    }
    float smax = red[0];
    __syncthreads();
    if (t < G_GR) red[t] = sim - smax;
    __syncthreads();
    for (int s = 64; s > 0; s >>= 1) {
        if (t < s) red[t] += red[t + s];
        __syncthreads();
    }
    if (t == 0) out[0] = -(red[0] / 128.f);
}

// ---------------------------------------------------------------------------
extern "C" void kernel_launch(void* const* d_in, const int* in_sizes, int n_in,
                              void* d_out, int out_size, void* d_ws, size_t ws_size,
                              hipStream_t stream) {
    const float4* X4      = (const float4*)d_in[0];
    const int*    subject = (const int*)d_in[1];
    const int*    labels  = (const int*)d_in[2];
    float*        out     = (float*)d_out;
    char*         ws      = (char*)d_ws;

    size_t o = 0;
    int*   hblk     = (int*)(ws + o);   o += (size_t)NBLK_S * G_GR * 4;     // 32 KiB
    int*   counts   = (int*)(ws + o);   o += 512;
    int*   offsets  = (int*)(ws + o);   o += 512;
    float* countsf  = (float*)(ws + o); o += 512;
    int*   perm     = (int*)(ws + o);   o += (size_t)BPTS * 4;              // 512 KiB
    float* part     = (float*)(ws + o); o += (size_t)G_GR * NSLC * 128 * 4; // 1 MiB
    float* centroid = (float*)(ws + o); o += (size_t)G_GR * D_DIM * 4;      // 64 KiB
    float* dpart    = (float*)(ws + o); o += (size_t)G_GR * NSLC * 4;       // 8 KiB

    k_hist   <<<NBLK_S, 256, 0, stream>>>(subject, labels, hblk);
    k_scatter<<<NBLK_S, 256, 0, stream>>>(subject, labels, hblk, counts, offsets, countsf, perm);
    k_psum   <<<G_GR * NSLC, 256, 0, stream>>>(X4, perm, offsets, counts, part);
    k_dist   <<<G_GR * NSLC, 256, 0, stream>>>(X4, perm, offsets, counts, part, centroid, dpart);
    k_final  <<<1, 512, 0, stream>>>(dpart, countsf, centroid, out);
}